// Round 7
// baseline (243.450 us; speedup 1.0000x reference)
//
#include <hip/hip_runtime.h>
#include <hip/hip_bf16.h>
#include <stdint.h>
#include <stddef.h>

typedef short bf16x8 __attribute__((ext_vector_type(8)));
typedef short s16x4 __attribute__((ext_vector_type(4)));
typedef float f32x4 __attribute__((ext_vector_type(4)));

#define HW 4096
#define WDIM 64

__device__ __forceinline__ short f2bf(float f) {
  union { __hip_bfloat16 b; short s; } u;
  u.b = __float2bfloat16(f);
  return u.s;
}
__device__ __forceinline__ float bf2f(short s) {
  union { unsigned u; float f; } u;
  u.u = ((unsigned)(unsigned short)s) << 16;
  return u.f;
}

// ---------------- prep: gather/convert weights (hi/lo split) + bias ----------------
__global__ void prep_weights(const float* __restrict__ w0, const float* __restrict__ w1,
                             const float* __restrict__ w2, const float* __restrict__ b0,
                             const float* __restrict__ b1, const float* __restrict__ b2,
                             const float* __restrict__ pw,
                             short* __restrict__ Wh, short* __restrict__ Wl,
                             short* __restrict__ Ph, short* __restrict__ Pl,
                             float* __restrict__ bias_sel) {
  int idx = blockIdx.x * 256 + threadIdx.x;
  if (idx < 768 * 256) {
    int j = idx >> 8;
    int h = (j & 255) >> 5;
    const float* w = (h < 4) ? w0 : ((h < 7) ? w1 : w2);
    float v = w[idx];
    short hi = f2bf(v);
    Wh[idx] = hi;
    Wl[idx] = f2bf(v - bf2f(hi));
  } else if (idx < 768 * 256 + 256 * 256) {
    int k = idx - 768 * 256;
    float v = pw[k];
    short hi = f2bf(v);
    Ph[k] = hi;
    Pl[k] = f2bf(v - bf2f(hi));
  } else if (idx < 768 * 256 + 256 * 256 + 768) {
    int j = idx - (768 * 256 + 256 * 256);
    int h = (j & 255) >> 5;
    const float* bb = (h < 4) ? b0 : ((h < 7) ? b1 : b2);
    bias_sel[j] = bb[j];
  }
}

// ---------------- transpose x: (B,256,HW) f32 -> XT (B,HW,256) bf16 hi/lo ----------------
__global__ void transpose_x(const float* __restrict__ x, short* __restrict__ XTh,
                            short* __restrict__ XTl) {
  __shared__ float tile[32][33];
  int b = blockIdx.z;
  int p0 = blockIdx.x * 32, c0 = blockIdx.y * 32;
  int tx = threadIdx.x, ty = threadIdx.y;       // 32 x 8
  const float* xb = x + (size_t)b * 256 * HW;
  #pragma unroll
  for (int i = 0; i < 32; i += 8)
    tile[ty + i][tx] = xb[(size_t)(c0 + ty + i) * HW + p0 + tx];
  __syncthreads();
  size_t ob = (size_t)b * HW * 256;
  #pragma unroll
  for (int i = 0; i < 32; i += 8) {
    float v = tile[tx][ty + i];
    short hi = f2bf(v);
    size_t o = ob + (size_t)(p0 + ty + i) * 256 + c0 + tx;
    XTh[o] = hi;
    XTl[o] = f2bf(v - bf2f(hi));
  }
}

// ---------------- split-bf16 MFMA GEMM, tile-parameterized ----------------
// C[b][m][p] = sum_c A[m,c]*Bm[b][p][c] + bias[m]; 3 MFMAs (hh+hl+lh).
// OUT=0: write qkv_t layout [b][t(3)][h(8)][p(4096)][d(32)] fp32 (float4 stores)
// OUT=1: write standard C[b][m][p] fp32
template <int BM, int BN, int OUT>
__global__ __launch_bounds__(256) void gemm_split(
    const short* __restrict__ Ah, const short* __restrict__ Al,
    const short* __restrict__ Bh, const short* __restrict__ Bl,
    const float* __restrict__ bias, float* __restrict__ C, int M) {
  constexpr int LD = 40;
  constexpr int AL = BM / 64, BL = BN / 64;
  constexpr int WM = BM / 2, WN = BN / 2;
  constexpr int MR = WM / 16, NR = WN / 16;
  __shared__ short Ash[BM * LD], Asl[BM * LD], Bsh[BN * LD], Bsl[BN * LD];
  int tid = threadIdx.x;
  int b = blockIdx.z;
  size_t aoff = (size_t)blockIdx.y * BM * 256;
  size_t boff = (size_t)b * HW * 256 + (size_t)blockIdx.x * BN * 256;
  int lane = tid & 63, wid = tid >> 6;
  int wm = wid >> 1, wn = wid & 1;
  int il = lane & 15, kg = lane >> 4;
  f32x4 acc[MR][NR] = {};
  int row_s = tid >> 2;
  int kk_s = (tid & 3) * 8;

  for (int kt = 0; kt < 256; kt += 32) {
    bf16x8 rah[AL], ral[AL], rbh[BL], rbl[BL];
    #pragma unroll
    for (int i = 0; i < AL; ++i) {
      size_t g = aoff + (size_t)(row_s + 64 * i) * 256 + kt + kk_s;
      rah[i] = *(const bf16x8*)&Ah[g];
      ral[i] = *(const bf16x8*)&Al[g];
    }
    #pragma unroll
    for (int i = 0; i < BL; ++i) {
      size_t g = boff + (size_t)(row_s + 64 * i) * 256 + kt + kk_s;
      rbh[i] = *(const bf16x8*)&Bh[g];
      rbl[i] = *(const bf16x8*)&Bl[g];
    }
    __syncthreads();
    #pragma unroll
    for (int i = 0; i < AL; ++i) {
      *(bf16x8*)&Ash[(row_s + 64 * i) * LD + kk_s] = rah[i];
      *(bf16x8*)&Asl[(row_s + 64 * i) * LD + kk_s] = ral[i];
    }
    #pragma unroll
    for (int i = 0; i < BL; ++i) {
      *(bf16x8*)&Bsh[(row_s + 64 * i) * LD + kk_s] = rbh[i];
      *(bf16x8*)&Bsl[(row_s + 64 * i) * LD + kk_s] = rbl[i];
    }
    __syncthreads();
    bf16x8 afh[MR], afl[MR], bfh[NR], bfl[NR];
    #pragma unroll
    for (int mr = 0; mr < MR; ++mr) {
      int r = (wm * WM + mr * 16 + il) * LD + kg * 8;
      afh[mr] = *(bf16x8*)&Ash[r];
      afl[mr] = *(bf16x8*)&Asl[r];
    }
    #pragma unroll
    for (int nr = 0; nr < NR; ++nr) {
      int r = (wn * WN + nr * 16 + il) * LD + kg * 8;
      bfh[nr] = *(bf16x8*)&Bsh[r];
      bfl[nr] = *(bf16x8*)&Bsl[r];
    }
    #pragma unroll
    for (int mr = 0; mr < MR; ++mr)
      #pragma unroll
      for (int nr = 0; nr < NR; ++nr) {
        acc[mr][nr] = __builtin_amdgcn_mfma_f32_16x16x32_bf16(afh[mr], bfh[nr], acc[mr][nr], 0, 0, 0);
        acc[mr][nr] = __builtin_amdgcn_mfma_f32_16x16x32_bf16(afh[mr], bfl[nr], acc[mr][nr], 0, 0, 0);
        acc[mr][nr] = __builtin_amdgcn_mfma_f32_16x16x32_bf16(afl[mr], bfh[nr], acc[mr][nr], 0, 0, 0);
      }
  }

  int m0 = blockIdx.y * BM, n0 = blockIdx.x * BN;
  #pragma unroll
  for (int mr = 0; mr < MR; ++mr) {
    #pragma unroll
    for (int nr = 0; nr < NR; ++nr) {
      int grow0 = m0 + wm * WM + mr * 16 + kg * 4;
      int gcol = n0 + wn * WN + nr * 16 + il;
      if (OUT == 0) {
        int t = grow0 >> 8, h = (grow0 >> 5) & 7, d0 = grow0 & 31;
        size_t base = (((size_t)(b * 3 + t) * 8 + h) << 17) + ((size_t)gcol << 5) + d0;
        f32x4 vv;
        #pragma unroll
        for (int r = 0; r < 4; ++r) vv[r] = acc[mr][nr][r] + bias[grow0 + r];
        *(f32x4*)&C[base] = vv;
      } else {
        size_t cbase = (size_t)b * M * HW;
        #pragma unroll
        for (int r = 0; r < 4; ++r)
          C[cbase + (size_t)(grow0 + r) * HW + gcol] = acc[mr][nr][r] + bias[grow0 + r];
      }
    }
  }
}

// ---------------- attention: d-split x8, 4-visit register pipeline ----------------
// qkv_t layout: [(b*3+t)*8+h][p][d=32] fp32. Lane = pl(0..7) + 8*dq(0..7).
// Visits processed in batches of 4: stage 4 K-rows + 4 V-rows in registers,
// then 4 independent dot/shuffle/exp chains, then 4 acc-FMA groups.
template <int KSZ, int DIL>
__device__ __forceinline__ void attn_wave(const float* __restrict__ qkvt,
                                          short* __restrict__ Yh, short* __restrict__ Yl,
                                          int b, int hq, int p0, int lane) {
  constexpr int R = KSZ / 2;
  constexpr int L = KSZ * KSZ;
  constexpr int NB = (L + 3) / 4;
  const float SCALE = 0.17677669529663687f;     // 32^-0.5
  int pl = lane & 7;
  int dq = lane >> 3;                            // 0..7
  int p = p0 + pl;
  const float* qp = qkvt + (((size_t)(b * 24 + hq)) << 17) + ((size_t)p << 5) + dq * 4;
  const float* kb = qkvt + (((size_t)(b * 24 + 8 + hq)) << 17) + dq * 4;
  const float* vb = qkvt + (((size_t)(b * 24 + 16 + hq)) << 17) + dq * 4;

  f32x4 q = *(const f32x4*)qp;
  #pragma unroll
  for (int j = 0; j < 4; ++j) q[j] *= SCALE;

  f32x4 acc = {0.f, 0.f, 0.f, 0.f};
  float denom = 0.f;
  int y = p >> 6, x = p & 63;

  #pragma unroll
  for (int g = 0; g < NB; ++g) {
    f32x4 kk[4], vv[4];
    bool val[4];
    // stage: 8 independent 16B loads
    #pragma unroll
    for (int j = 0; j < 4; ++j) {
      constexpr_helper:;
      const int i = 0;  // placeholder to keep scope clean
      (void)i;
      int vi = g * 4 + j;
      if (vi < L) {
        int dy = vi / KSZ - R, dx = vi % KSZ - R;
        int ny = y + dy * DIL, nx = x + dx * DIL;
        val[j] = (((unsigned)ny < WDIM) & ((unsigned)nx < WDIM));
        int pp = val[j] ? (ny * WDIM + nx) : p;
        kk[j] = *(const f32x4*)(kb + ((size_t)pp << 5));
        vv[j] = *(const f32x4*)(vb + ((size_t)pp << 5));
      }
    }
    // compute: 4 independent shuffle chains
    float e[4];
    #pragma unroll
    for (int j = 0; j < 4; ++j) {
      int vi = g * 4 + j;
      if (vi < L) {
        float s = q[0] * kk[j][0] + q[1] * kk[j][1] + q[2] * kk[j][2] + q[3] * kk[j][3];
        s += __shfl_xor(s, 8);
        s += __shfl_xor(s, 16);
        s += __shfl_xor(s, 32);
        e[j] = __expf(val[j] ? s : 0.0f);        // OOB -> exp(0)=1 in denom
        denom += e[j];
      }
    }
    // accumulate
    #pragma unroll
    for (int j = 0; j < 4; ++j) {
      int vi = g * 4 + j;
      if (vi < L) {
        float en = val[j] ? e[j] : 0.0f;         // OOB -> 0 in numerator
        #pragma unroll
        for (int k = 0; k < 4; ++k) acc[k] += en * vv[j][k];
      }
    }
  }

  float inv = 1.0f / denom;
  size_t yo = ((size_t)b * HW + p) * 256 + hq * 32 + dq * 4;
  s16x4 oh, ol;
  #pragma unroll
  for (int j = 0; j < 4; ++j) {
    float v = acc[j] * inv;
    short hi = f2bf(v);
    oh[j] = hi;
    ol[j] = f2bf(v - bf2f(hi));
  }
  *(s16x4*)&Yh[yo] = oh;
  *(s16x4*)&Yl[yo] = ol;
}

// XCD-aware mapping: blockIdx%8 selects the XCD (HW round-robin); combo c
// (b,h pair, 0..15) pinned to XCD c&7 so each XCD's L2 caches only 2 heads.
// bid = xcd + 8*(tile + 128*half), c = xcd + 8*half, tile 0..127 (32 p each).
__global__ __launch_bounds__(256, 8) void attn_all(const float* __restrict__ qkvt,
                                                   short* __restrict__ Yh,
                                                   short* __restrict__ Yl) {
  int tid = threadIdx.x;
  int lane = tid & 63, wave = tid >> 6;
  int bid = blockIdx.x;
  int xcd = bid & 7;
  int idx = bid >> 3;                            // 0..255
  int half = idx >> 7;                           // 0,1
  int tile = idx & 127;
  int c = xcd + 8 * half;                        // combo 0..15
  int p0 = tile * 32 + wave * 8;
  if (c < 8) {
    int h = c >> 1, b = c & 1;                   // ksz5, h 0..3
    attn_wave<5, 1>(qkvt, Yh, Yl, b, h, p0, lane);
  } else if (c < 14) {
    int s = c - 8;
    int h = 4 + (s >> 1), b = s & 1;             // ksz7, h 4..6
    attn_wave<7, 2>(qkvt, Yh, Yl, b, h, p0, lane);
  } else {
    int b = c & 1;                               // ksz9, h 7
    attn_wave<9, 3>(qkvt, Yh, Yl, b, 7, p0, lane);
  }
}

// ---------------- launch ----------------
extern "C" void kernel_launch(void* const* d_in, const int* in_sizes, int n_in,
                              void* d_out, int out_size, void* d_ws, size_t ws_size,
                              hipStream_t stream) {
  const float* x  = (const float*)d_in[0];
  const float* w0 = (const float*)d_in[1];
  const float* b0 = (const float*)d_in[2];
  const float* w1 = (const float*)d_in[3];
  const float* b1 = (const float*)d_in[4];
  const float* w2 = (const float*)d_in[5];
  const float* b2 = (const float*)d_in[6];
  const float* pw = (const float*)d_in[7];
  const float* pb = (const float*)d_in[8];

  char* ws = (char*)d_ws;
  float* qkvt = (float*)ws; ws += (size_t)2 * 768 * HW * 4;   // [b][t][h][p][d]
  short* XTh = (short*)ws;  ws += (size_t)2 * HW * 256 * 2;
  short* XTl = (short*)ws;  ws += (size_t)2 * HW * 256 * 2;
  short* Yh  = (short*)ws;  ws += (size_t)2 * HW * 256 * 2;
  short* Yl  = (short*)ws;  ws += (size_t)2 * HW * 256 * 2;
  short* Wh  = (short*)ws;  ws += (size_t)768 * 256 * 2;
  short* Wl  = (short*)ws;  ws += (size_t)768 * 256 * 2;
  short* Ph  = (short*)ws;  ws += (size_t)256 * 256 * 2;
  short* Pl  = (short*)ws;  ws += (size_t)256 * 256 * 2;
  float* bsel= (float*)ws;  ws += 4096;

  prep_weights<<<1027, 256, 0, stream>>>(w0, w1, w2, b0, b1, b2, pw, Wh, Wl, Ph, Pl, bsel);
  transpose_x<<<dim3(128, 8, 2), dim3(32, 8), 0, stream>>>(x, XTh, XTl);
  gemm_split<64, 128, 0><<<dim3(32, 12, 2), 256, 0, stream>>>(Wh, Wl, XTh, XTl, bsel, qkvt, 768);
  attn_all<<<2048, 256, 0, stream>>>(qkvt, Yh, Yl);
  gemm_split<64, 64, 1><<<dim3(64, 4, 2), 256, 0, stream>>>(Ph, Pl, Yh, Yl, pb, (float*)d_out, 256);
}

// Round 9
// 205.553 us; speedup vs baseline: 1.1844x; 1.1844x over previous
//
#include <hip/hip_runtime.h>
#include <hip/hip_bf16.h>
#include <stdint.h>
#include <stddef.h>

typedef short bf16x8 __attribute__((ext_vector_type(8)));
typedef short s16x4 __attribute__((ext_vector_type(4)));
typedef float f32x4 __attribute__((ext_vector_type(4)));

#define HW 4096
#define WDIM 64

__device__ __forceinline__ short f2bf(float f) {
  union { __hip_bfloat16 b; short s; } u;
  u.b = __float2bfloat16(f);
  return u.s;
}
__device__ __forceinline__ float bf2f(short s) {
  union { unsigned u; float f; } u;
  u.u = ((unsigned)(unsigned short)s) << 16;
  return u.f;
}

// ---------------- prep: gather/convert weights (hi/lo split) + bias ----------------
__global__ void prep_weights(const float* __restrict__ w0, const float* __restrict__ w1,
                             const float* __restrict__ w2, const float* __restrict__ b0,
                             const float* __restrict__ b1, const float* __restrict__ b2,
                             const float* __restrict__ pw,
                             short* __restrict__ Wh, short* __restrict__ Wl,
                             short* __restrict__ Ph, short* __restrict__ Pl,
                             float* __restrict__ bias_sel) {
  int idx = blockIdx.x * 256 + threadIdx.x;
  if (idx < 768 * 256) {
    int j = idx >> 8;
    int h = (j & 255) >> 5;
    const float* w = (h < 4) ? w0 : ((h < 7) ? w1 : w2);
    float v = w[idx];
    short hi = f2bf(v);
    Wh[idx] = hi;
    Wl[idx] = f2bf(v - bf2f(hi));
  } else if (idx < 768 * 256 + 256 * 256) {
    int k = idx - 768 * 256;
    float v = pw[k];
    short hi = f2bf(v);
    Ph[k] = hi;
    Pl[k] = f2bf(v - bf2f(hi));
  } else if (idx < 768 * 256 + 256 * 256 + 768) {
    int j = idx - (768 * 256 + 256 * 256);
    int h = (j & 255) >> 5;
    const float* bb = (h < 4) ? b0 : ((h < 7) ? b1 : b2);
    bias_sel[j] = bb[j];
  }
}

// ---------------- transpose x: (B,256,HW) f32 -> XT (B,HW,256) bf16 hi/lo ----------------
__global__ void transpose_x(const float* __restrict__ x, short* __restrict__ XTh,
                            short* __restrict__ XTl) {
  __shared__ float tile[32][33];
  int b = blockIdx.z;
  int p0 = blockIdx.x * 32, c0 = blockIdx.y * 32;
  int tx = threadIdx.x, ty = threadIdx.y;       // 32 x 8
  const float* xb = x + (size_t)b * 256 * HW;
  #pragma unroll
  for (int i = 0; i < 32; i += 8)
    tile[ty + i][tx] = xb[(size_t)(c0 + ty + i) * HW + p0 + tx];
  __syncthreads();
  size_t ob = (size_t)b * HW * 256;
  #pragma unroll
  for (int i = 0; i < 32; i += 8) {
    float v = tile[tx][ty + i];
    short hi = f2bf(v);
    size_t o = ob + (size_t)(p0 + ty + i) * 256 + c0 + tx;
    XTh[o] = hi;
    XTl[o] = f2bf(v - bf2f(hi));
  }
}

// ---------------- split-bf16 MFMA GEMM, tile-parameterized ----------------
// C[b][m][p] = sum_c A[m,c]*Bm[b][p][c] + bias[m]; 3 MFMAs (hh+hl+lh).
// OUT=0: write qkv_t layout [b][t(3)][h(8)][p(4096)][d(32)] fp32 (float4 stores)
// OUT=1: write standard C[b][m][p] fp32
template <int BM, int BN, int OUT>
__global__ __launch_bounds__(256) void gemm_split(
    const short* __restrict__ Ah, const short* __restrict__ Al,
    const short* __restrict__ Bh, const short* __restrict__ Bl,
    const float* __restrict__ bias, float* __restrict__ C, int M) {
  constexpr int LD = 40;
  constexpr int AL = BM / 64, BL = BN / 64;
  constexpr int WM = BM / 2, WN = BN / 2;
  constexpr int MR = WM / 16, NR = WN / 16;
  __shared__ short Ash[BM * LD], Asl[BM * LD], Bsh[BN * LD], Bsl[BN * LD];
  int tid = threadIdx.x;
  int b = blockIdx.z;
  size_t aoff = (size_t)blockIdx.y * BM * 256;
  size_t boff = (size_t)b * HW * 256 + (size_t)blockIdx.x * BN * 256;
  int lane = tid & 63, wid = tid >> 6;
  int wm = wid >> 1, wn = wid & 1;
  int il = lane & 15, kg = lane >> 4;
  f32x4 acc[MR][NR] = {};
  int row_s = tid >> 2;
  int kk_s = (tid & 3) * 8;

  for (int kt = 0; kt < 256; kt += 32) {
    bf16x8 rah[AL], ral[AL], rbh[BL], rbl[BL];
    #pragma unroll
    for (int i = 0; i < AL; ++i) {
      size_t g = aoff + (size_t)(row_s + 64 * i) * 256 + kt + kk_s;
      rah[i] = *(const bf16x8*)&Ah[g];
      ral[i] = *(const bf16x8*)&Al[g];
    }
    #pragma unroll
    for (int i = 0; i < BL; ++i) {
      size_t g = boff + (size_t)(row_s + 64 * i) * 256 + kt + kk_s;
      rbh[i] = *(const bf16x8*)&Bh[g];
      rbl[i] = *(const bf16x8*)&Bl[g];
    }
    __syncthreads();
    #pragma unroll
    for (int i = 0; i < AL; ++i) {
      *(bf16x8*)&Ash[(row_s + 64 * i) * LD + kk_s] = rah[i];
      *(bf16x8*)&Asl[(row_s + 64 * i) * LD + kk_s] = ral[i];
    }
    #pragma unroll
    for (int i = 0; i < BL; ++i) {
      *(bf16x8*)&Bsh[(row_s + 64 * i) * LD + kk_s] = rbh[i];
      *(bf16x8*)&Bsl[(row_s + 64 * i) * LD + kk_s] = rbl[i];
    }
    __syncthreads();
    bf16x8 afh[MR], afl[MR], bfh[NR], bfl[NR];
    #pragma unroll
    for (int mr = 0; mr < MR; ++mr) {
      int r = (wm * WM + mr * 16 + il) * LD + kg * 8;
      afh[mr] = *(bf16x8*)&Ash[r];
      afl[mr] = *(bf16x8*)&Asl[r];
    }
    #pragma unroll
    for (int nr = 0; nr < NR; ++nr) {
      int r = (wn * WN + nr * 16 + il) * LD + kg * 8;
      bfh[nr] = *(bf16x8*)&Bsh[r];
      bfl[nr] = *(bf16x8*)&Bsl[r];
    }
    #pragma unroll
    for (int mr = 0; mr < MR; ++mr)
      #pragma unroll
      for (int nr = 0; nr < NR; ++nr) {
        acc[mr][nr] = __builtin_amdgcn_mfma_f32_16x16x32_bf16(afh[mr], bfh[nr], acc[mr][nr], 0, 0, 0);
        acc[mr][nr] = __builtin_amdgcn_mfma_f32_16x16x32_bf16(afh[mr], bfl[nr], acc[mr][nr], 0, 0, 0);
        acc[mr][nr] = __builtin_amdgcn_mfma_f32_16x16x32_bf16(afl[mr], bfh[nr], acc[mr][nr], 0, 0, 0);
      }
  }

  int m0 = blockIdx.y * BM, n0 = blockIdx.x * BN;
  #pragma unroll
  for (int mr = 0; mr < MR; ++mr) {
    #pragma unroll
    for (int nr = 0; nr < NR; ++nr) {
      int grow0 = m0 + wm * WM + mr * 16 + kg * 4;
      int gcol = n0 + wn * WN + nr * 16 + il;
      if (OUT == 0) {
        int t = grow0 >> 8, h = (grow0 >> 5) & 7, d0 = grow0 & 31;
        size_t base = (((size_t)(b * 3 + t) * 8 + h) << 17) + ((size_t)gcol << 5) + d0;
        f32x4 vv;
        #pragma unroll
        for (int r = 0; r < 4; ++r) vv[r] = acc[mr][nr][r] + bias[grow0 + r];
        *(f32x4*)&C[base] = vv;
      } else {
        size_t cbase = (size_t)b * M * HW;
        #pragma unroll
        for (int r = 0; r < 4; ++r)
          C[cbase + (size_t)(grow0 + r) * HW + gcol] = acc[mr][nr][r] + bias[grow0 + r];
      }
    }
  }
}

// ---------------- attention: d-split x8, explicit double-buffered pipeline ----------------
// qkv_t layout: [(b*3+t)*8+h][p][d=32] fp32. Lane = pl(0..7) + 8*dq(0..7).
// Visits in groups of 4; two register banks (A/B): load bank for group g+1 is
// issued in program order BEFORE the compute of group g -> 8 visits in flight.

template <int KSZ, int DIL, int L>
__device__ __forceinline__ void loadg(int g, f32x4 (&kk)[4], f32x4 (&vv)[4], bool (&vm)[4],
                                      const float* __restrict__ kb,
                                      const float* __restrict__ vb,
                                      int y, int x, int p) {
  constexpr int R = KSZ / 2;
  #pragma unroll
  for (int j = 0; j < 4; ++j) {
    int vi = g * 4 + j;                          // compile-time after unroll
    if (vi < L) {
      int dy = vi / KSZ - R, dx = vi % KSZ - R;
      int ny = y + dy * DIL, nx = x + dx * DIL;
      bool val = (((unsigned)ny < WDIM) & ((unsigned)nx < WDIM));
      vm[j] = val;
      int pp = val ? (ny * WDIM + nx) : p;       // always in-bounds
      kk[j] = *(const f32x4*)(kb + ((size_t)pp << 5));
      vv[j] = *(const f32x4*)(vb + ((size_t)pp << 5));
    }
  }
}

template <int L>
__device__ __forceinline__ void compg(int g, const f32x4 (&kk)[4], const f32x4 (&vv)[4],
                                      const bool (&vm)[4], const f32x4& q,
                                      f32x4& acc, float& denom) {
  float s[4], t[4];
  #pragma unroll
  for (int j = 0; j < 4; ++j)
    if (g * 4 + j < L)
      s[j] = q[0] * kk[j][0] + q[1] * kk[j][1] + q[2] * kk[j][2] + q[3] * kk[j][3];
  // interleaved 3-level butterfly: 4 independent shuffles per level
  #pragma unroll
  for (int j = 0; j < 4; ++j) if (g * 4 + j < L) t[j] = __shfl_xor(s[j], 8);
  #pragma unroll
  for (int j = 0; j < 4; ++j) if (g * 4 + j < L) s[j] += t[j];
  #pragma unroll
  for (int j = 0; j < 4; ++j) if (g * 4 + j < L) t[j] = __shfl_xor(s[j], 16);
  #pragma unroll
  for (int j = 0; j < 4; ++j) if (g * 4 + j < L) s[j] += t[j];
  #pragma unroll
  for (int j = 0; j < 4; ++j) if (g * 4 + j < L) t[j] = __shfl_xor(s[j], 32);
  #pragma unroll
  for (int j = 0; j < 4; ++j) if (g * 4 + j < L) s[j] += t[j];
  #pragma unroll
  for (int j = 0; j < 4; ++j) {
    if (g * 4 + j < L) {
      float e = __expf(vm[j] ? s[j] : 0.0f);     // OOB -> exp(0)=1 in denom
      denom += e;
      float en = vm[j] ? e : 0.0f;               // OOB -> 0 in numerator
      #pragma unroll
      for (int k2 = 0; k2 < 4; ++k2) acc[k2] += en * vv[j][k2];
    }
  }
}

template <int KSZ, int DIL>
__device__ __forceinline__ void attn_wave(const float* __restrict__ qkvt,
                                          short* __restrict__ Yh, short* __restrict__ Yl,
                                          int b, int hq, int p0, int lane) {
  constexpr int L = KSZ * KSZ;
  constexpr int NB = (L + 3) / 4;
  const float SCALE = 0.17677669529663687f;     // 32^-0.5
  int pl = lane & 7;
  int dq = lane >> 3;                            // 0..7
  int p = p0 + pl;
  const float* qp = qkvt + (((size_t)(b * 24 + hq)) << 17) + ((size_t)p << 5) + dq * 4;
  const float* kb = qkvt + (((size_t)(b * 24 + 8 + hq)) << 17) + dq * 4;
  const float* vb = qkvt + (((size_t)(b * 24 + 16 + hq)) << 17) + dq * 4;

  f32x4 q = *(const f32x4*)qp;
  #pragma unroll
  for (int j = 0; j < 4; ++j) q[j] *= SCALE;

  f32x4 acc = {0.f, 0.f, 0.f, 0.f};
  float denom = 0.f;
  int y = p >> 6, x = p & 63;

  f32x4 kA[4], vA[4]; bool mA[4];
  f32x4 kB[4], vB[4]; bool mB[4];
  loadg<KSZ, DIL, L>(0, kA, vA, mA, kb, vb, y, x, p);
  #pragma unroll
  for (int g = 0; g < NB; ++g) {
    if ((g & 1) == 0) {
      if (g + 1 < NB) loadg<KSZ, DIL, L>(g + 1, kB, vB, mB, kb, vb, y, x, p);
      compg<L>(g, kA, vA, mA, q, acc, denom);
    } else {
      if (g + 1 < NB) loadg<KSZ, DIL, L>(g + 1, kA, vA, mA, kb, vb, y, x, p);
      compg<L>(g, kB, vB, mB, q, acc, denom);
    }
  }

  float inv = 1.0f / denom;
  size_t yo = ((size_t)b * HW + p) * 256 + hq * 32 + dq * 4;
  s16x4 oh, ol;
  #pragma unroll
  for (int j = 0; j < 4; ++j) {
    float v = acc[j] * inv;
    short hi = f2bf(v);
    oh[j] = hi;
    ol[j] = f2bf(v - bf2f(hi));
  }
  *(s16x4*)&Yh[yo] = oh;
  *(s16x4*)&Yl[yo] = ol;
}

// waves (global id gw, 8192 total): [0,4096) ksz5 h0-3, [4096,7168) ksz7 h4-6,
// [7168,8192) ksz9 h7. Each wave: 8 positions. 2048 blocks x 4 waves.
// __launch_bounds__(256,4): VGPR cap 128 so the A/B staging banks fit.
__global__ __launch_bounds__(256, 4) void attn_all(const float* __restrict__ qkvt,
                                                   short* __restrict__ Yh,
                                                   short* __restrict__ Yl) {
  int tid = threadIdx.x;
  int lane = tid & 63, wave = tid >> 6;
  int gw = blockIdx.x * 4 + wave;
  if (gw < 4096) {
    int tile = gw & 511;
    int t2 = gw >> 9;
    int b = t2 & 1, h = t2 >> 1;                 // h 0..3
    attn_wave<5, 1>(qkvt, Yh, Yl, b, h, tile * 8, lane);
  } else if (gw < 7168) {
    int s = gw - 4096;
    int tile = s & 511;
    int t2 = s >> 9;
    int b = t2 & 1, h = 4 + (t2 >> 1);           // h 4..6
    attn_wave<7, 2>(qkvt, Yh, Yl, b, h, tile * 8, lane);
  } else {
    int s = gw - 7168;
    int tile = s & 511;
    int b = s >> 9;                              // h = 7
    attn_wave<9, 3>(qkvt, Yh, Yl, b, 7, tile * 8, lane);
  }
}

// ---------------- launch ----------------
extern "C" void kernel_launch(void* const* d_in, const int* in_sizes, int n_in,
                              void* d_out, int out_size, void* d_ws, size_t ws_size,
                              hipStream_t stream) {
  const float* x  = (const float*)d_in[0];
  const float* w0 = (const float*)d_in[1];
  const float* b0 = (const float*)d_in[2];
  const float* w1 = (const float*)d_in[3];
  const float* b1 = (const float*)d_in[4];
  const float* w2 = (const float*)d_in[5];
  const float* b2 = (const float*)d_in[6];
  const float* pw = (const float*)d_in[7];
  const float* pb = (const float*)d_in[8];

  char* ws = (char*)d_ws;
  float* qkvt = (float*)ws; ws += (size_t)2 * 768 * HW * 4;   // [b][t][h][p][d]
  short* XTh = (short*)ws;  ws += (size_t)2 * HW * 256 * 2;
  short* XTl = (short*)ws;  ws += (size_t)2 * HW * 256 * 2;
  short* Yh  = (short*)ws;  ws += (size_t)2 * HW * 256 * 2;
  short* Yl  = (short*)ws;  ws += (size_t)2 * HW * 256 * 2;
  short* Wh  = (short*)ws;  ws += (size_t)768 * 256 * 2;
  short* Wl  = (short*)ws;  ws += (size_t)768 * 256 * 2;
  short* Ph  = (short*)ws;  ws += (size_t)256 * 256 * 2;
  short* Pl  = (short*)ws;  ws += (size_t)256 * 256 * 2;
  float* bsel= (float*)ws;  ws += 4096;

  prep_weights<<<1027, 256, 0, stream>>>(w0, w1, w2, b0, b1, b2, pw, Wh, Wl, Ph, Pl, bsel);
  transpose_x<<<dim3(128, 8, 2), dim3(32, 8), 0, stream>>>(x, XTh, XTl);
  gemm_split<64, 128, 0><<<dim3(32, 12, 2), 256, 0, stream>>>(Wh, Wl, XTh, XTl, bsel, qkvt, 768);
  attn_all<<<2048, 256, 0, stream>>>(qkvt, Yh, Yl);
  gemm_split<64, 64, 1><<<dim3(64, 4, 2), 256, 0, stream>>>(Ph, Pl, Yh, Yl, pb, (float*)d_out, 256);
}